// Round 5
// baseline (1379.409 us; speedup 1.0000x reference)
//
#include <hip/hip_runtime.h>
#include <math.h>

// ---------------------------------------------------------------------------
// MLPEncoder (NRI encoder) on MI355X — round 5:
//   - MODE 3: x2 skip-rows prestaged to LDS (coalesced, one-time) so the
//     K-loop never waits on HBM/L3 latency.
//   - Epilogue reductions (e2n / BN-stats) moved to registers + shuffles.
// Pipeline structure otherwise identical to round 4.
// ---------------------------------------------------------------------------

typedef unsigned short ushort_t;
typedef __bf16 bf16x8 __attribute__((ext_vector_type(8)));
typedef float  f32x4  __attribute__((ext_vector_type(4)));

#define E_EDGES 9900
#define NNODE   100
#define HID     256
#define M_BIG   316800
#define M_SMALL 3200

__device__ __forceinline__ float bf2f(ushort_t u) {
    union { unsigned int i; float f; } v; v.i = ((unsigned int)u) << 16; return v.f;
}
__device__ __forceinline__ ushort_t f2bf(float f) {
    union { float f; unsigned int i; } v; v.f = f;
    return (ushort_t)((v.i + 0x7fffu + ((v.i >> 16) & 1u)) >> 16);   // RNE
}
__device__ __forceinline__ float elu_f(float x) {
    return x > 0.f ? x : (expf(x) - 1.f);
}

// ---- merged weight convert+transpose: 4 matrices, 64x64 tiles -------------
__global__ __launch_bounds__(256)
void wcvt4_kernel(const float* __restrict__ W0, const float* __restrict__ W1,
                  const float* __restrict__ W2, const float* __restrict__ W3,
                  ushort_t* __restrict__ T0, ushort_t* __restrict__ T1,
                  ushort_t* __restrict__ T2, ushort_t* __restrict__ T3)
{
    int bid = blockIdx.x;
    const float* W; ushort_t* WT; int K, tile;
    if (bid < 32)      { W = W0; WT = T0; K = 512; tile = bid; }
    else if (bid < 48) { W = W1; WT = T1; K = 256; tile = bid - 32; }
    else if (bid < 96) { W = W2; WT = T2; K = 768; tile = bid - 48; }
    else               { W = W3; WT = T3; K = 256; tile = bid - 96; }
    int k0 = (tile >> 2) * 64, c0 = (tile & 3) * 64;
    __shared__ float S[64][65];
    int t = threadIdx.x;
    #pragma unroll
    for (int i = 0; i < 16; ++i) {
        int idx = t + i * 256;
        S[idx >> 6][idx & 63] = W[(size_t)(k0 + (idx >> 6)) * 256 + c0 + (idx & 63)];
    }
    __syncthreads();
    int col = t & 63;
    int kb  = (t >> 6) * 16;
    ushort_t* dst = WT + (size_t)(c0 + col) * K + k0 + kb;
    #pragma unroll
    for (int jj = 0; jj < 4; ++jj) {
        ushort4 u;
        u.x = f2bf(S[kb + 4 * jj + 0][col]);
        u.y = f2bf(S[kb + 4 * jj + 1][col]);
        u.z = f2bf(S[kb + 4 * jj + 2][col]);
        u.w = f2bf(S[kb + 4 * jj + 3][col]);
        *(ushort4*)(dst + 4 * jj) = u;
    }
}

// ---- fused small 2-layer fp32 MLP: X[3200,K0] -> ELU MLP -> bf16 [3200,256]
#define FMA_ROW(ri, xs) \
    acc[ri][0] = fmaf(xs, w.x, acc[ri][0]); \
    acc[ri][1] = fmaf(xs, w.y, acc[ri][1]); \
    acc[ri][2] = fmaf(xs, w.z, acc[ri][2]); \
    acc[ri][3] = fmaf(xs, w.w, acc[ri][3]);

__global__ __launch_bounds__(256, 2)
void fused_small(const float* __restrict__ X, int K0, float xscale,
                 const float* __restrict__ W1, const float* __restrict__ b1,
                 const float* __restrict__ W2, const float* __restrict__ b2,
                 ushort_t* __restrict__ Yb)
{
    __shared__ float Xs[32][68];
    __shared__ float Ws[32][256];
    __shared__ ushort_t Hs[64][264];
    const int tid = threadIdx.x;
    const int Rbase = blockIdx.x * 64;
    const int c0 = (tid & 63) * 4;
    const int r0 = (tid >> 6) * 16;
    const int r_st = tid & 63;
    const int kb = (tid >> 6) * 8;

    float acc[16][4];
    #pragma unroll
    for (int i = 0; i < 16; ++i)
        #pragma unroll
        for (int j = 0; j < 4; ++j) acc[i][j] = 0.f;

    const int nch = (K0 + 31) >> 5;
    for (int kc = 0; kc < nch; ++kc) {
        if (kc) __syncthreads();
        {
            int kg = kc * 32 + kb;
            const float* p = X + (size_t)(Rbase + r_st) * K0 + kg;
            float v[8];
            if (kg + 8 <= K0) {
                float4 a = *(const float4*)p;
                float4 b = *(const float4*)(p + 4);
                v[0]=a.x; v[1]=a.y; v[2]=a.z; v[3]=a.w;
                v[4]=b.x; v[5]=b.y; v[6]=b.z; v[7]=b.w;
            } else {
                #pragma unroll
                for (int j = 0; j < 8; ++j) v[j] = (kg + j < K0) ? p[j] : 0.f;
            }
            #pragma unroll
            for (int j = 0; j < 8; ++j) Xs[kb + j][r_st] = v[j];
        }
        #pragma unroll
        for (int m = 0; m < 8; ++m) {
            int f  = tid + m * 256;
            int kk = f >> 6;
            int cc = (f & 63) * 4;
            int kg = kc * 32 + kk;
            float4 w = (kg < K0) ? *(const float4*)&W1[(size_t)kg * 256 + cc]
                                 : make_float4(0.f, 0.f, 0.f, 0.f);
            *(float4*)&Ws[kk][cc] = w;
        }
        __syncthreads();
        #pragma unroll 8
        for (int kk = 0; kk < 32; ++kk) {
            float4 w = *(const float4*)&Ws[kk][c0];
            #pragma unroll
            for (int i = 0; i < 4; ++i) {
                float4 x = *(const float4*)&Xs[kk][r0 + 4 * i];
                FMA_ROW(4 * i + 0, x.x)
                FMA_ROW(4 * i + 1, x.y)
                FMA_ROW(4 * i + 2, x.z)
                FMA_ROW(4 * i + 3, x.w)
            }
        }
    }
    {
        float4 bv = *(const float4*)&b1[c0];
        #pragma unroll
        for (int i = 0; i < 16; ++i) {
            ushort4 u;
            u.x = f2bf(elu_f(acc[i][0] * xscale + bv.x));
            u.y = f2bf(elu_f(acc[i][1] * xscale + bv.y));
            u.z = f2bf(elu_f(acc[i][2] * xscale + bv.z));
            u.w = f2bf(elu_f(acc[i][3] * xscale + bv.w));
            *(ushort4*)&Hs[r0 + i][c0] = u;
        }
    }
    #pragma unroll
    for (int i = 0; i < 16; ++i)
        #pragma unroll
        for (int j = 0; j < 4; ++j) acc[i][j] = 0.f;
    for (int kc = 0; kc < 8; ++kc) {
        __syncthreads();
        {
            union { uint4 qv; ushort_t s[8]; } u;
            u.qv = *(const uint4*)&Hs[r_st][kc * 32 + kb];
            #pragma unroll
            for (int j = 0; j < 8; ++j) Xs[kb + j][r_st] = bf2f(u.s[j]);
        }
        #pragma unroll
        for (int m = 0; m < 8; ++m) {
            int f  = tid + m * 256;
            int kk = f >> 6;
            int cc = (f & 63) * 4;
            *(float4*)&Ws[kk][cc] = *(const float4*)&W2[(size_t)(kc * 32 + kk) * 256 + cc];
        }
        __syncthreads();
        #pragma unroll 8
        for (int kk = 0; kk < 32; ++kk) {
            float4 w = *(const float4*)&Ws[kk][c0];
            #pragma unroll
            for (int i = 0; i < 4; ++i) {
                float4 x = *(const float4*)&Xs[kk][r0 + 4 * i];
                FMA_ROW(4 * i + 0, x.x)
                FMA_ROW(4 * i + 1, x.y)
                FMA_ROW(4 * i + 2, x.z)
                FMA_ROW(4 * i + 3, x.w)
            }
        }
    }
    {
        float4 bv = *(const float4*)&b2[c0];
        #pragma unroll
        for (int i = 0; i < 16; ++i) {
            int R = Rbase + r0 + i;
            ushort4 u;
            u.x = f2bf(elu_f(acc[i][0] + bv.x));
            u.y = f2bf(elu_f(acc[i][1] + bv.y));
            u.z = f2bf(elu_f(acc[i][2] + bv.z));
            u.w = f2bf(elu_f(acc[i][3] + bv.w));
            *(ushort4*)&Yb[(size_t)R * 256 + c0] = u;
        }
    }
}

// ---- fused 2-layer MFMA MLP ----------------------------------------------
// MODE 2: L1 in = [h1b[send]|h1b[recv]] (K1=512); epilogue: e2n -> aux
// MODE 3: L1 in = [h3b[send]|h3b[recv]|x2[R]] (K1=768); x2 prestaged in LDS;
//         in-place over X2; epilogue: BN stats -> aux
template<int MODE>
__global__ __launch_bounds__(256, 3)
void fused_mfma(const ushort_t* __restrict__ Gb,
                const ushort_t* __restrict__ X2,
                const ushort_t* __restrict__ W1T,   // [256][K1] bf16
                const float* __restrict__ bias1,
                const ushort_t* __restrict__ W2T,   // [256][256] bf16
                const float* __restrict__ bias2,
                ushort_t* __restrict__ Y,
                float* __restrict__ aux)
{
    constexpr int K1  = (MODE == 2) ? 512 : 768;
    constexpr int NG  = 16;                    // global-gather k-chunks (both)
    constexpr int NL  = (MODE == 3) ? 8 : 0;   // LDS (prestaged x2) k-chunks
    __shared__ ushort_t Hb[64][264];

    const int tid = threadIdx.x;
    const int w = tid >> 6;
    const int l = tid & 63;
    const int ln15 = l & 15;
    const int q = l >> 4;
    const int klane = 8 * q;
    const int Rbase = blockIdx.x * 64;

    // ---- MODE 3: prestage x2 rows Rbase..Rbase+63 into Hb (coalesced) ----
    if (MODE == 3) {
        const int row = tid >> 2;
        const int cj  = (tid & 3) * 64;
        const ushort_t* src = X2 + (size_t)(Rbase + row) * 256 + cj;
        uint4 v[8];
        #pragma unroll
        for (int i = 0; i < 8; ++i) v[i] = *(const uint4*)(src + i * 8);
        #pragma unroll
        for (int i = 0; i < 8; ++i) *(uint4*)&Hb[row][cj + i * 8] = v[i];
        __syncthreads();
    }

    // per-lane gather offsets for the 4 row-tiles
    int oS[4], oR[4];
    #pragma unroll
    for (int r = 0; r < 4; ++r) {
        int R = Rbase + 16 * r + ln15;
        int b = R / E_EDGES;
        int e = R - b * E_EDGES;
        int i = e / 99;
        int kk = e - i * 99;
        int j = kk + (kk >= i ? 1 : 0);
        oS[r] = (b * NNODE + j) * HID;
        oR[r] = (b * NNODE + i) * HID;
    }
    int wch[4];
    #pragma unroll
    for (int c = 0; c < 4; ++c) wch[c] = (w * 64 + 16 * c + ln15) * K1;

    f32x4 acc[4][4];
    #pragma unroll
    for (int r = 0; r < 4; ++r)
        #pragma unroll
        for (int c = 0; c < 4; ++c)
            acc[r][c][0] = acc[r][c][1] = acc[r][c][2] = acc[r][c][3] = 0.f;

    // ---------------- layer 1 ----------------
    auto loadA1 = [&](int kc, bf16x8 a[4]) {   // kc < NG: global gathers only
        #pragma unroll
        for (int r = 0; r < 4; ++r) {
            if (kc < 8) a[r] = *(const bf16x8*)(Gb + oS[r] + kc * 32 + klane);
            else        a[r] = *(const bf16x8*)(Gb + oR[r] + (kc - 8) * 32 + klane);
        }
    };
    auto loadB1 = [&](int kc, bf16x8 b[4]) {
        #pragma unroll
        for (int c = 0; c < 4; ++c)
            b[c] = *(const bf16x8*)(W1T + wch[c] + kc * 32 + klane);
    };

    {
        bf16x8 a0[4], b0[4];
        loadA1(0, a0);
        loadB1(0, b0);
        #pragma unroll
        for (int kc = 0; kc < NG + NL; ++kc) {
            bf16x8 a1[4], b1[4];
            if (kc + 1 < NG + NL) {
                if (kc + 1 < NG) loadA1(kc + 1, a1);
                else {
                    #pragma unroll
                    for (int r = 0; r < 4; ++r)
                        a1[r] = *(const bf16x8*)&Hb[16 * r + ln15][(kc + 1 - NG) * 32 + klane];
                }
                loadB1(kc + 1, b1);
            }
            #pragma unroll
            for (int r = 0; r < 4; ++r)
                #pragma unroll
                for (int c = 0; c < 4; ++c)
                    acc[r][c] = __builtin_amdgcn_mfma_f32_16x16x32_bf16(b0[c], a0[r], acc[r][c], 0, 0, 0);
            #pragma unroll
            for (int r = 0; r < 4; ++r) { a0[r] = a1[r]; b0[r] = b1[r]; }
        }
    }
    if (MODE == 3) __syncthreads();   // all Hb (x2) reads done before overwrite

    // hidden = ELU(acc + b1) -> Hb
    #pragma unroll
    for (int c = 0; c < 4; ++c) {
        float4 bv = *(const float4*)&bias1[w * 64 + 16 * c + 4 * q];
        #pragma unroll
        for (int r = 0; r < 4; ++r) {
            ushort4 u;
            u.x = f2bf(elu_f(acc[r][c][0] + bv.x));
            u.y = f2bf(elu_f(acc[r][c][1] + bv.y));
            u.z = f2bf(elu_f(acc[r][c][2] + bv.z));
            u.w = f2bf(elu_f(acc[r][c][3] + bv.w));
            *(ushort4*)&Hb[16 * r + ln15][w * 64 + 16 * c + 4 * q] = u;
        }
    }
    __syncthreads();

    // ---------------- layer 2: K=256, A from Hb ----------------
    #pragma unroll
    for (int r = 0; r < 4; ++r)
        #pragma unroll
        for (int c = 0; c < 4; ++c)
            acc[r][c][0] = acc[r][c][1] = acc[r][c][2] = acc[r][c][3] = 0.f;

    int wch2[4];
    #pragma unroll
    for (int c = 0; c < 4; ++c) wch2[c] = (w * 64 + 16 * c + ln15) * 256;
    {
        bf16x8 b0[4];
        #pragma unroll
        for (int c = 0; c < 4; ++c)
            b0[c] = *(const bf16x8*)(W2T + wch2[c] + klane);
        #pragma unroll
        for (int kc = 0; kc < 8; ++kc) {
            bf16x8 af[4];
            #pragma unroll
            for (int r = 0; r < 4; ++r)
                af[r] = *(const bf16x8*)&Hb[16 * r + ln15][kc * 32 + klane];
            bf16x8 b1[4];
            if (kc < 7) {
                #pragma unroll
                for (int c = 0; c < 4; ++c)
                    b1[c] = *(const bf16x8*)(W2T + wch2[c] + (kc + 1) * 32 + klane);
            }
            #pragma unroll
            for (int r = 0; r < 4; ++r)
                #pragma unroll
                for (int c = 0; c < 4; ++c)
                    acc[r][c] = __builtin_amdgcn_mfma_f32_16x16x32_bf16(b0[c], af[r], acc[r][c], 0, 0, 0);
            #pragma unroll
            for (int c = 0; c < 4; ++c) b0[c] = b1[c];
        }
    }
    __syncthreads();    // Hb reads done before overwrite

    // out = ELU(acc + b2): keep fp32 in acc (for reductions) + park bf16 in Hb
    #pragma unroll
    for (int c = 0; c < 4; ++c) {
        float4 bv = *(const float4*)&bias2[w * 64 + 16 * c + 4 * q];
        #pragma unroll
        for (int r = 0; r < 4; ++r) {
            acc[r][c][0] = elu_f(acc[r][c][0] + bv.x);
            acc[r][c][1] = elu_f(acc[r][c][1] + bv.y);
            acc[r][c][2] = elu_f(acc[r][c][2] + bv.z);
            acc[r][c][3] = elu_f(acc[r][c][3] + bv.w);
            ushort4 u;
            u.x = f2bf(acc[r][c][0]);
            u.y = f2bf(acc[r][c][1]);
            u.z = f2bf(acc[r][c][2]);
            u.w = f2bf(acc[r][c][3]);
            *(ushort4*)&Hb[16 * r + ln15][w * 64 + 16 * c + 4 * q] = u;
        }
    }
    __syncthreads();

    // coalesced global write from Hb
    #pragma unroll
    for (int m = 0; m < 8; ++m) {
        int ch = tid + m * 256;
        int row = ch >> 5;
        int o = (ch & 31) * 8;
        *(uint4*)&Y[((size_t)(Rbase + row)) * 256 + o] = *(const uint4*)&Hb[row][o];
    }

    // ---- register epilogue reductions (no LDS loops) ----
    if (MODE == 2) {
        // e2n: segmented sum over the block's 64 edges (<=2 receiver segments)
        int bn0 = Rbase / 99;
        int S = 99 - (Rbase - bn0 * 99);          // edges in first segment
        bool two = (S < 64);
        #pragma unroll
        for (int c = 0; c < 4; ++c) {
            float s0[4] = {0.f, 0.f, 0.f, 0.f};
            float s1[4] = {0.f, 0.f, 0.f, 0.f};
            #pragma unroll
            for (int r = 0; r < 4; ++r) {
                bool first = (16 * r + ln15) < S;
                #pragma unroll
                for (int g = 0; g < 4; ++g) {
                    float v = acc[r][c][g];
                    if (first) s0[g] += v; else s1[g] += v;
                }
            }
            #pragma unroll
            for (int g = 0; g < 4; ++g)
                #pragma unroll
                for (int m = 1; m < 16; m <<= 1) {
                    s0[g] += __shfl_xor(s0[g], m, 64);
                    s1[g] += __shfl_xor(s1[g], m, 64);
                }
            if (ln15 == 0) {
                #pragma unroll
                for (int g = 0; g < 4; ++g) {
                    int ch = w * 64 + 16 * c + 4 * q + g;
                    atomicAdd(&aux[(size_t)bn0 * 256 + ch], s0[g]);
                    if (two) atomicAdd(&aux[(size_t)(bn0 + 1) * 256 + ch], s1[g]);
                }
            }
        }
    } else {
        // BN stats: per-channel sum and sumsq over 64 edges
        #pragma unroll
        for (int c = 0; c < 4; ++c) {
            float s0[4] = {0.f, 0.f, 0.f, 0.f};
            float q2[4] = {0.f, 0.f, 0.f, 0.f};
            #pragma unroll
            for (int r = 0; r < 4; ++r)
                #pragma unroll
                for (int g = 0; g < 4; ++g) {
                    float v = acc[r][c][g];
                    s0[g] += v;
                    q2[g] = fmaf(v, v, q2[g]);
                }
            #pragma unroll
            for (int g = 0; g < 4; ++g)
                #pragma unroll
                for (int m = 1; m < 16; m <<= 1) {
                    s0[g] += __shfl_xor(s0[g], m, 64);
                    q2[g] += __shfl_xor(q2[g], m, 64);
                }
            if (ln15 == 0) {
                #pragma unroll
                for (int g = 0; g < 4; ++g) {
                    int ch = w * 64 + 16 * c + 4 * q + g;
                    atomicAdd(&aux[ch], s0[g]);
                    atomicAdd(&aux[256 + ch], q2[g]);
                }
            }
        }
    }
}

// ---- fold BN + fc into Wfold[256][2], bfold[2] ----------------------------
__global__ __launch_bounds__(256)
void fold_kernel(const float* __restrict__ stats,
                 const float* __restrict__ gamma, const float* __restrict__ beta,
                 const float* __restrict__ fcW, const float* __restrict__ fcb,
                 float* __restrict__ fold)
{
    __shared__ float red0[256], red1[256];
    int c = threadIdx.x;
    float mean  = stats[c] * (1.f / M_BIG);
    float var   = stats[256 + c] * (1.f / M_BIG) - mean * mean;
    float inv   = rsqrtf(var + 1e-5f);
    float scale = inv * gamma[c];
    float sh    = beta[c] - mean * scale;
    float w0 = fcW[c * 2 + 0], w1 = fcW[c * 2 + 1];
    fold[c * 2 + 0] = scale * w0;
    fold[c * 2 + 1] = scale * w1;
    red0[c] = sh * w0;
    red1[c] = sh * w1;
    __syncthreads();
    for (int off = 128; off > 0; off >>= 1) {
        if (c < off) { red0[c] += red0[c + off]; red1[c] += red1[c + off]; }
        __syncthreads();
    }
    if (c == 0) {
        fold[512] = red0[0] + fcb[0];
        fold[513] = red1[0] + fcb[1];
    }
}

// ---- final: out[R][2] = x4_row . Wfold + bfold  (wave per row) ------------
__global__ __launch_bounds__(256)
void final_kernel(const ushort_t* __restrict__ x4, const float* __restrict__ fold,
                  float* __restrict__ out)
{
    int tid  = threadIdx.x;
    int lane = tid & 63;
    int wave = tid >> 6;
    int R = blockIdx.x * 4 + wave;
    int c0 = lane * 4;
    union { uint2 qv; ushort_t s[4]; } u;
    u.qv = *(const uint2*)(x4 + (size_t)R * 256 + c0);
    float a0 = 0.f, a1 = 0.f;
    #pragma unroll
    for (int j = 0; j < 4; ++j) {
        float v = bf2f(u.s[j]);
        a0 = fmaf(v, fold[(c0 + j) * 2 + 0], a0);
        a1 = fmaf(v, fold[(c0 + j) * 2 + 1], a1);
    }
    #pragma unroll
    for (int off = 32; off > 0; off >>= 1) {
        a0 += __shfl_down(a0, off);
        a1 += __shfl_down(a1, off);
    }
    if (lane == 0) {
        out[(size_t)R * 2 + 0] = a0 + fold[512];
        out[(size_t)R * 2 + 1] = a1 + fold[513];
    }
}

extern "C" void kernel_launch(void* const* d_in, const int* in_sizes, int n_in,
                              void* d_out, int out_size, void* d_ws, size_t ws_size,
                              hipStream_t stream)
{
    (void)in_sizes; (void)n_in; (void)out_size; (void)ws_size;

    const float* inputs = (const float*)d_in[0];
    const float* m1W1 = (const float*)d_in[3];
    const float* m1b1 = (const float*)d_in[4];
    const float* m1W2 = (const float*)d_in[5];
    const float* m1b2 = (const float*)d_in[6];
    const float* m2W1 = (const float*)d_in[7];
    const float* m2b1 = (const float*)d_in[8];
    const float* m2W2 = (const float*)d_in[9];
    const float* m2b2 = (const float*)d_in[10];
    const float* m3W1 = (const float*)d_in[11];
    const float* m3b1 = (const float*)d_in[12];
    const float* m3W2 = (const float*)d_in[13];
    const float* m3b2 = (const float*)d_in[14];
    const float* m4W1 = (const float*)d_in[15];
    const float* m4b1 = (const float*)d_in[16];
    const float* m4W2 = (const float*)d_in[17];
    const float* m4b2 = (const float*)d_in[18];
    const float* gamma = (const float*)d_in[19];
    const float* beta  = (const float*)d_in[20];
    const float* fcW   = (const float*)d_in[21];
    const float* fcb   = (const float*)d_in[22];
    float* out = (float*)d_out;

    // ---- workspace layout (~168 MB) ----
    char* ws = (char*)d_ws;
    const size_t BIGB  = (size_t)M_BIG * 256 * 2;
    const size_t HB    = (size_t)M_SMALL * 256 * 2;
    const size_t SMALL = (size_t)M_SMALL * 256 * 4;
    ushort_t* bigX     = (ushort_t*)ws;
    ushort_t* hbuf     = (ushort_t*)(ws + BIGB);
    float*    incoming = (float*)(ws + BIGB + HB);
    float*    stats    = (float*)(ws + BIGB + HB + SMALL);
    float*    fold     = stats + 512;
    ushort_t* w1t      = (ushort_t*)(ws + BIGB + HB + SMALL + 8192);
    ushort_t* w2t      = w1t + 512 * 256;
    ushort_t* w4at     = w2t + 256 * 256;
    ushort_t* w4bt     = w4at + 768 * 256;

    hipMemsetAsync(stats, 0, 2048, stream);
    hipMemsetAsync(incoming, 0, SMALL, stream);

    dim3 blk(256);
    wcvt4_kernel<<<112, blk, 0, stream>>>(m2W1, m2W2, m4W1, m4W2, w1t, w2t, w4at, w4bt);
    fused_small<<<M_SMALL / 64, blk, 0, stream>>>(inputs, 200, 1.f, m1W1, m1b1, m1W2, m1b2, hbuf);
    fused_mfma<2><<<M_BIG / 64, blk, 0, stream>>>(hbuf, bigX, w1t, m2b1, w2t, m2b2, bigX, incoming);
    fused_small<<<M_SMALL / 64, blk, 0, stream>>>(incoming, 256, 1.f / 9900.f, m3W1, m3b1, m3W2, m3b2, hbuf);
    fused_mfma<3><<<M_BIG / 64, blk, 0, stream>>>(hbuf, bigX, w4at, m4b1, w4bt, m4b2, bigX, stats);
    fold_kernel<<<1, blk, 0, stream>>>(stats, gamma, beta, fcW, fcb, fold);
    final_kernel<<<M_BIG / 4, blk, 0, stream>>>(bigX, fold, out);
}

// Round 6
// 889.276 us; speedup vs baseline: 1.5512x; 1.5512x over previous
//
#include <hip/hip_runtime.h>
#include <math.h>

// ---------------------------------------------------------------------------
// MLPEncoder (NRI encoder) on MI355X — round 6: algebraic restructure.
//   concat(h[send],h[recv])@W1  ==  (h@W1a)[send] + (h@W1b)[recv]
// so the K=512/768 gather-GEMMs collapse to:
//   P2=h1@W1a+b1, Q2=h1@W1b (tiny GEMMs), then per-edge
//   hidden = ELU(P2[send]+Q2[recv]);  x2 = ELU(hidden@W2+b2)        (41.6 GF)
//   pre    = P4[send]+Q4[recv] + x2@W4a3; hidden=ELU(pre)
//   x4     = ELU(hidden@W4b+b2)                                     (83.2 GF)
// Edge kernels: A-tiles staged ONCE per block in LDS (dense, coalesced, no
// gather in K-loop), W-frags direct from L2 (chan-major WT) with 1-deep
// prefetch, swapped-operand MFMA (R4-verified C layout: edge=ln15,
// chan=4q+reg). Epilogues: R4-style LDS loops (shuffle version regressed).
// ---------------------------------------------------------------------------

typedef unsigned short ushort_t;
typedef __bf16 bf16x8 __attribute__((ext_vector_type(8)));
typedef float  f32x4  __attribute__((ext_vector_type(4)));

#define E_EDGES 9900
#define NNODE   100
#define HID     256
#define M_BIG   316800
#define M_SMALL 3200

__device__ __forceinline__ float bf2f(ushort_t u) {
    union { unsigned int i; float f; } v; v.i = ((unsigned int)u) << 16; return v.f;
}
__device__ __forceinline__ ushort_t f2bf(float f) {
    union { float f; unsigned int i; } v; v.f = f;
    return (ushort_t)((v.i + 0x7fffu + ((v.i >> 16) & 1u)) >> 16);   // RNE
}
__device__ __forceinline__ float elu_f(float x) {
    return x > 0.f ? x : (expf(x) - 1.f);
}

// ---- convert+transpose 3 [256,256] fp32 matrices -> bf16 WT[chan][256] ----
__global__ __launch_bounds__(256)
void wcvt3_kernel(const float* __restrict__ W0, const float* __restrict__ W1,
                  const float* __restrict__ W2,
                  ushort_t* __restrict__ T0, ushort_t* __restrict__ T1,
                  ushort_t* __restrict__ T2)
{
    int bid = blockIdx.x;
    const float* W; ushort_t* WT; int tile;
    if (bid < 16)      { W = W0; WT = T0; tile = bid; }
    else if (bid < 32) { W = W1; WT = T1; tile = bid - 16; }
    else               { W = W2; WT = T2; tile = bid - 32; }
    int k0 = (tile >> 2) * 64, c0 = (tile & 3) * 64;
    __shared__ float S[64][65];
    int t = threadIdx.x;
    #pragma unroll
    for (int i = 0; i < 16; ++i) {
        int idx = t + i * 256;
        S[idx >> 6][idx & 63] = W[(size_t)(k0 + (idx >> 6)) * 256 + c0 + (idx & 63)];
    }
    __syncthreads();
    int col = t & 63;
    int kb  = (t >> 6) * 16;
    ushort_t* dst = WT + (size_t)(c0 + col) * 256 + k0 + kb;
    #pragma unroll
    for (int jj = 0; jj < 4; ++jj) {
        ushort4 u;
        u.x = f2bf(S[kb + 4 * jj + 0][col]);
        u.y = f2bf(S[kb + 4 * jj + 1][col]);
        u.z = f2bf(S[kb + 4 * jj + 2][col]);
        u.w = f2bf(S[kb + 4 * jj + 3][col]);
        *(ushort4*)(dst + 4 * jj) = u;
    }
}

// ---- fused small 2-layer fp32 MLP: X[3200,K0] -> ELU MLP -> fp32 [3200,256]
#define FMA_ROW(ri, xs) \
    acc[ri][0] = fmaf(xs, w.x, acc[ri][0]); \
    acc[ri][1] = fmaf(xs, w.y, acc[ri][1]); \
    acc[ri][2] = fmaf(xs, w.z, acc[ri][2]); \
    acc[ri][3] = fmaf(xs, w.w, acc[ri][3]);

__global__ __launch_bounds__(256, 2)
void fused_small(const float* __restrict__ X, int K0, float xscale,
                 const float* __restrict__ W1, const float* __restrict__ b1,
                 const float* __restrict__ W2, const float* __restrict__ b2,
                 float* __restrict__ Yf)
{
    __shared__ float Xs[32][68];
    __shared__ float Ws[32][256];
    __shared__ float Hs[64][257];
    const int tid = threadIdx.x;
    const int Rbase = blockIdx.x * 64;
    const int c0 = (tid & 63) * 4;
    const int r0 = (tid >> 6) * 16;
    const int r_st = tid & 63;
    const int kb = (tid >> 6) * 8;

    float acc[16][4];
    #pragma unroll
    for (int i = 0; i < 16; ++i)
        #pragma unroll
        for (int j = 0; j < 4; ++j) acc[i][j] = 0.f;

    const int nch = (K0 + 31) >> 5;
    for (int kc = 0; kc < nch; ++kc) {
        if (kc) __syncthreads();
        {
            int kg = kc * 32 + kb;
            const float* p = X + (size_t)(Rbase + r_st) * K0 + kg;
            float v[8];
            if (kg + 8 <= K0) {
                float4 a = *(const float4*)p;
                float4 b = *(const float4*)(p + 4);
                v[0]=a.x; v[1]=a.y; v[2]=a.z; v[3]=a.w;
                v[4]=b.x; v[5]=b.y; v[6]=b.z; v[7]=b.w;
            } else {
                #pragma unroll
                for (int j = 0; j < 8; ++j) v[j] = (kg + j < K0) ? p[j] : 0.f;
            }
            #pragma unroll
            for (int j = 0; j < 8; ++j) Xs[kb + j][r_st] = v[j];
        }
        #pragma unroll
        for (int m = 0; m < 8; ++m) {
            int f  = tid + m * 256;
            int kk = f >> 6;
            int cc = (f & 63) * 4;
            int kg = kc * 32 + kk;
            float4 w = (kg < K0) ? *(const float4*)&W1[(size_t)kg * 256 + cc]
                                 : make_float4(0.f, 0.f, 0.f, 0.f);
            *(float4*)&Ws[kk][cc] = w;
        }
        __syncthreads();
        #pragma unroll 8
        for (int kk = 0; kk < 32; ++kk) {
            float4 w = *(const float4*)&Ws[kk][c0];
            #pragma unroll
            for (int i = 0; i < 4; ++i) {
                float4 x = *(const float4*)&Xs[kk][r0 + 4 * i];
                FMA_ROW(4 * i + 0, x.x)
                FMA_ROW(4 * i + 1, x.y)
                FMA_ROW(4 * i + 2, x.z)
                FMA_ROW(4 * i + 3, x.w)
            }
        }
    }
    {
        float4 bv = *(const float4*)&b1[c0];
        #pragma unroll
        for (int i = 0; i < 16; ++i) {
            Hs[r0 + i][c0 + 0] = elu_f(acc[i][0] * xscale + bv.x);
            Hs[r0 + i][c0 + 1] = elu_f(acc[i][1] * xscale + bv.y);
            Hs[r0 + i][c0 + 2] = elu_f(acc[i][2] * xscale + bv.z);
            Hs[r0 + i][c0 + 3] = elu_f(acc[i][3] * xscale + bv.w);
        }
    }
    #pragma unroll
    for (int i = 0; i < 16; ++i)
        #pragma unroll
        for (int j = 0; j < 4; ++j) acc[i][j] = 0.f;
    for (int kc = 0; kc < 8; ++kc) {
        __syncthreads();
        {
            #pragma unroll
            for (int j = 0; j < 8; ++j) Xs[kb + j][r_st] = Hs[r_st][kc * 32 + kb + j];
        }
        #pragma unroll
        for (int m = 0; m < 8; ++m) {
            int f  = tid + m * 256;
            int kk = f >> 6;
            int cc = (f & 63) * 4;
            *(float4*)&Ws[kk][cc] = *(const float4*)&W2[(size_t)(kc * 32 + kk) * 256 + cc];
        }
        __syncthreads();
        #pragma unroll 8
        for (int kk = 0; kk < 32; ++kk) {
            float4 w = *(const float4*)&Ws[kk][c0];
            #pragma unroll
            for (int i = 0; i < 4; ++i) {
                float4 x = *(const float4*)&Xs[kk][r0 + 4 * i];
                FMA_ROW(4 * i + 0, x.x)
                FMA_ROW(4 * i + 1, x.y)
                FMA_ROW(4 * i + 2, x.z)
                FMA_ROW(4 * i + 3, x.w)
            }
        }
    }
    {
        float4 bv = *(const float4*)&b2[c0];
        #pragma unroll
        for (int i = 0; i < 16; ++i) {
            int R = Rbase + r0 + i;
            *(float4*)&Yf[(size_t)R * 256 + c0] = make_float4(
                elu_f(acc[i][0] + bv.x), elu_f(acc[i][1] + bv.y),
                elu_f(acc[i][2] + bv.z), elu_f(acc[i][3] + bv.w));
        }
    }
}

// ---- P/Q partial GEMMs: P = X@Wa + biasA (no act), Q = X@Wb (bf16 out) ----
__global__ __launch_bounds__(256, 2)
void pq_gemm(const float* __restrict__ X,
             const float* __restrict__ Wa, const float* __restrict__ Wb_,
             const float* __restrict__ biasA,
             ushort_t* __restrict__ Yp, ushort_t* __restrict__ Yq)
{
    const int bid = blockIdx.x;
    const float* W; const float* bias; ushort_t* Y; int Rbase;
    if (bid < 50) { W = Wa;  bias = biasA;  Y = Yp; Rbase = bid * 64; }
    else          { W = Wb_; bias = nullptr; Y = Yq; Rbase = (bid - 50) * 64; }

    __shared__ float Xs[32][68];
    __shared__ float Ws[32][256];
    const int tid = threadIdx.x;
    const int c0 = (tid & 63) * 4;
    const int r0 = (tid >> 6) * 16;
    const int r_st = tid & 63;
    const int kb = (tid >> 6) * 8;

    float acc[16][4];
    #pragma unroll
    for (int i = 0; i < 16; ++i)
        #pragma unroll
        for (int j = 0; j < 4; ++j) acc[i][j] = 0.f;

    for (int kc = 0; kc < 8; ++kc) {
        if (kc) __syncthreads();
        {
            const float* p = X + (size_t)(Rbase + r_st) * 256 + kc * 32 + kb;
            float4 a = *(const float4*)p;
            float4 b = *(const float4*)(p + 4);
            Xs[kb + 0][r_st] = a.x; Xs[kb + 1][r_st] = a.y;
            Xs[kb + 2][r_st] = a.z; Xs[kb + 3][r_st] = a.w;
            Xs[kb + 4][r_st] = b.x; Xs[kb + 5][r_st] = b.y;
            Xs[kb + 6][r_st] = b.z; Xs[kb + 7][r_st] = b.w;
        }
        #pragma unroll
        for (int m = 0; m < 8; ++m) {
            int f  = tid + m * 256;
            int kk = f >> 6;
            int cc = (f & 63) * 4;
            *(float4*)&Ws[kk][cc] = *(const float4*)&W[(size_t)(kc * 32 + kk) * 256 + cc];
        }
        __syncthreads();
        #pragma unroll 8
        for (int kk = 0; kk < 32; ++kk) {
            float4 w = *(const float4*)&Ws[kk][c0];
            #pragma unroll
            for (int i = 0; i < 4; ++i) {
                float4 x = *(const float4*)&Xs[kk][r0 + 4 * i];
                FMA_ROW(4 * i + 0, x.x)
                FMA_ROW(4 * i + 1, x.y)
                FMA_ROW(4 * i + 2, x.z)
                FMA_ROW(4 * i + 3, x.w)
            }
        }
    }
    float4 bv = bias ? *(const float4*)&bias[c0] : make_float4(0.f, 0.f, 0.f, 0.f);
    #pragma unroll
    for (int i = 0; i < 16; ++i) {
        int R = Rbase + r0 + i;
        ushort4 u;
        u.x = f2bf(acc[i][0] + bv.x);
        u.y = f2bf(acc[i][1] + bv.y);
        u.z = f2bf(acc[i][2] + bv.z);
        u.w = f2bf(acc[i][3] + bv.w);
        *(ushort4*)&Y[(size_t)R * 256 + c0] = u;
    }
}

// ---- edge kernel A (MLP2): hidden=ELU(P[j]+Q[i]); x2=ELU(hidden@W2+b2) ----
__global__ __launch_bounds__(256, 3)
void edge_mlp2(const ushort_t* __restrict__ Pb, const ushort_t* __restrict__ Qb,
               const ushort_t* __restrict__ W2T,   // [chan][256] bf16
               const float* __restrict__ b2,
               ushort_t* __restrict__ Y, float* __restrict__ aux)
{
    __shared__ ushort_t As[64][264];    // hidden, then x2 park
    const int tid = threadIdx.x;
    const int w = tid >> 6;
    const int l = tid & 63;
    const int ln15 = l & 15;
    const int q = l >> 4;
    const int klane = 8 * q;
    const int Rbase = blockIdx.x * 64;

    // phase 1: hidden tile (coalesced row gathers of P/Q, elementwise ELU)
    {
        int row = tid >> 2;
        int R = Rbase + row;
        int b = R / E_EDGES;
        int e = R - b * E_EDGES;
        int i = e / 99;
        int k = e - 99 * i;
        int j = k + (k >= i ? 1 : 0);
        const ushort_t* prow = Pb + (size_t)(b * NNODE + j) * HID;
        const ushort_t* qrow = Qb + (size_t)(b * NNODE + i) * HID;
        int off = (tid & 3) * 8;
        #pragma unroll
        for (int u = 0; u < 8; ++u) {
            int o = off + u * 32;
            union { uint4 v; ushort_t s[8]; } pu, qu, hu;
            pu.v = *(const uint4*)(prow + o);
            qu.v = *(const uint4*)(qrow + o);
            #pragma unroll
            for (int x = 0; x < 8; ++x)
                hu.s[x] = f2bf(elu_f(bf2f(pu.s[x]) + bf2f(qu.s[x])));
            *(uint4*)&As[row][o] = hu.v;
        }
    }
    __syncthreads();

    // GEMM: acc = hidden @ W2 (swapped-operand MFMA, W-frags from L2)
    f32x4 acc[4][4];
    #pragma unroll
    for (int r = 0; r < 4; ++r)
        #pragma unroll
        for (int c = 0; c < 4; ++c)
            acc[r][c][0] = acc[r][c][1] = acc[r][c][2] = acc[r][c][3] = 0.f;
    int wch[4];
    #pragma unroll
    for (int c = 0; c < 4; ++c) wch[c] = (w * 64 + 16 * c + ln15) * 256;
    {
        bf16x8 wf0[4];
        #pragma unroll
        for (int c = 0; c < 4; ++c)
            wf0[c] = *(const bf16x8*)(W2T + wch[c] + klane);
        #pragma unroll
        for (int kc = 0; kc < 8; ++kc) {
            bf16x8 wf1[4];
            if (kc < 7) {
                #pragma unroll
                for (int c = 0; c < 4; ++c)
                    wf1[c] = *(const bf16x8*)(W2T + wch[c] + (kc + 1) * 32 + klane);
            }
            bf16x8 af[4];
            #pragma unroll
            for (int r = 0; r < 4; ++r)
                af[r] = *(const bf16x8*)&As[16 * r + ln15][kc * 32 + klane];
            #pragma unroll
            for (int r = 0; r < 4; ++r)
                #pragma unroll
                for (int c = 0; c < 4; ++c)
                    acc[r][c] = __builtin_amdgcn_mfma_f32_16x16x32_bf16(wf0[c], af[r], acc[r][c], 0, 0, 0);
            #pragma unroll
            for (int c = 0; c < 4; ++c) wf0[c] = wf1[c];
        }
    }
    __syncthreads();    // hidden reads done

    // park x2 = ELU(acc + b2)  (lane: edge=16r+ln15, chans w*64+16c+4q+g)
    #pragma unroll
    for (int c = 0; c < 4; ++c) {
        float4 bv = *(const float4*)&b2[w * 64 + 16 * c + 4 * q];
        #pragma unroll
        for (int r = 0; r < 4; ++r) {
            ushort4 u;
            u.x = f2bf(elu_f(acc[r][c][0] + bv.x));
            u.y = f2bf(elu_f(acc[r][c][1] + bv.y));
            u.z = f2bf(elu_f(acc[r][c][2] + bv.z));
            u.w = f2bf(elu_f(acc[r][c][3] + bv.w));
            *(ushort4*)&As[16 * r + ln15][w * 64 + 16 * c + 4 * q] = u;
        }
    }
    __syncthreads();

    // coalesced global write
    #pragma unroll
    for (int m = 0; m < 8; ++m) {
        int ch = tid + m * 256;
        int row = ch >> 5;
        int o = (ch & 31) * 8;
        *(uint4*)&Y[((size_t)(Rbase + row)) * 256 + o] = *(const uint4*)&As[row][o];
    }

    // e2n epilogue (R4-style LDS loop; receiver segments are contiguous)
    {
        int c = tid;
        int bn = Rbase / 99;
        int left = 99 - (Rbase - bn * 99);
        float s = 0.f;
        for (int r = 0; r < 64; ++r) {
            s += bf2f(As[r][c]);
            if (--left == 0) { atomicAdd(&aux[(size_t)bn * 256 + c], s); s = 0.f; ++bn; left = 99; }
        }
        atomicAdd(&aux[(size_t)bn * 256 + c], s);
    }
}

// ---- edge kernel B (MLP4): pre=P[j]+Q[i]+x2@W4a3; x4=ELU(ELU(pre)@W4b+b2) -
__global__ __launch_bounds__(256, 2)
void edge_mlp4(const ushort_t* __restrict__ Pb, const ushort_t* __restrict__ Qb,
               const ushort_t* __restrict__ X2,
               const ushort_t* __restrict__ WaT,   // [chan][256] bf16
               const ushort_t* __restrict__ WbT,   // [chan][256] bf16
               const float* __restrict__ b2,
               ushort_t* __restrict__ Y, float* __restrict__ aux)
{
    __shared__ ushort_t As[64][264];    // x2 tile, then hidden
    __shared__ ushort_t PQ[64][264];    // P+Q tile, then x4 park
    const int tid = threadIdx.x;
    const int w = tid >> 6;
    const int l = tid & 63;
    const int ln15 = l & 15;
    const int q = l >> 4;
    const int klane = 8 * q;
    const int Rbase = blockIdx.x * 64;

    // phase 0: stage x2 tile + PQ tile (coalesced)
    {
        int row = tid >> 2;
        int R = Rbase + row;
        int b = R / E_EDGES;
        int e = R - b * E_EDGES;
        int i = e / 99;
        int k = e - 99 * i;
        int j = k + (k >= i ? 1 : 0);
        const ushort_t* xrow = X2 + (size_t)R * 256;
        const ushort_t* prow = Pb + (size_t)(b * NNODE + j) * HID;
        const ushort_t* qrow = Qb + (size_t)(b * NNODE + i) * HID;
        int off = (tid & 3) * 8;
        #pragma unroll
        for (int u = 0; u < 8; ++u) {
            int o = off + u * 32;
            *(uint4*)&As[row][o] = *(const uint4*)(xrow + o);
            union { uint4 v; ushort_t s[8]; } pu, qu, hu;
            pu.v = *(const uint4*)(prow + o);
            qu.v = *(const uint4*)(qrow + o);
            #pragma unroll
            for (int x = 0; x < 8; ++x)
                hu.s[x] = f2bf(bf2f(pu.s[x]) + bf2f(qu.s[x]));   // no ELU here
            *(uint4*)&PQ[row][o] = hu.v;
        }
    }
    __syncthreads();

    f32x4 acc[4][4];
    int wch[4];
    #pragma unroll
    for (int c = 0; c < 4; ++c) wch[c] = (w * 64 + 16 * c + ln15) * 256;

    // L1 GEMM: acc = x2tile @ W4a3
    #pragma unroll
    for (int r = 0; r < 4; ++r)
        #pragma unroll
        for (int c = 0; c < 4; ++c)
            acc[r][c][0] = acc[r][c][1] = acc[r][c][2] = acc[r][c][3] = 0.f;
    {
        bf16x8 wf0[4];
        #pragma unroll
        for (int c = 0; c < 4; ++c)
            wf0[c] = *(const bf16x8*)(WaT + wch[c] + klane);
        #pragma unroll
        for (int kc = 0; kc < 8; ++kc) {
            bf16x8 wf1[4];
            if (kc < 7) {
                #pragma unroll
                for (int c = 0; c < 4; ++c)
                    wf1[c] = *(const bf16x8*)(WaT + wch[c] + (kc + 1) * 32 + klane);
            }
            bf16x8 af[4];
            #pragma unroll
            for (int r = 0; r < 4; ++r)
                af[r] = *(const bf16x8*)&As[16 * r + ln15][kc * 32 + klane];
            #pragma unroll
            for (int r = 0; r < 4; ++r)
                #pragma unroll
                for (int c = 0; c < 4; ++c)
                    acc[r][c] = __builtin_amdgcn_mfma_f32_16x16x32_bf16(wf0[c], af[r], acc[r][c], 0, 0, 0);
            #pragma unroll
            for (int c = 0; c < 4; ++c) wf0[c] = wf1[c];
        }
    }
    __syncthreads();    // x2 tile reads done

    // hidden = ELU(acc + PQ) -> As
    #pragma unroll
    for (int c = 0; c < 4; ++c) {
        #pragma unroll
        for (int r = 0; r < 4; ++r) {
            union { ushort4 v; ushort_t s[4]; } pq;
            pq.v = *(const ushort4*)&PQ[16 * r + ln15][w * 64 + 16 * c + 4 * q];
            ushort4 u;
            u.x = f2bf(elu_f(acc[r][c][0] + bf2f(pq.s[0])));
            u.y = f2bf(elu_f(acc[r][c][1] + bf2f(pq.s[1])));
            u.z = f2bf(elu_f(acc[r][c][2] + bf2f(pq.s[2])));
            u.w = f2bf(elu_f(acc[r][c][3] + bf2f(pq.s[3])));
            *(ushort4*)&As[16 * r + ln15][w * 64 + 16 * c + 4 * q] = u;
        }
    }
    __syncthreads();

    // L2 GEMM: acc = hidden @ W4b
    #pragma unroll
    for (int r = 0; r < 4; ++r)
        #pragma unroll
        for (int c = 0; c < 4; ++c)
            acc[r][c][0] = acc[r][c][1] = acc[r][c][2] = acc[r][c][3] = 0.f;
    {
        bf16x8 wf0[4];
        #pragma unroll
        for (int c = 0; c < 4; ++c)
            wf0[c] = *(const bf16x8*)(WbT + wch[c] + klane);
        #pragma unroll
        for (int kc = 0; kc < 8; ++kc) {
            bf16x8 wf1[4];
            if (kc < 7) {
                #pragma unroll
                for (int c = 0; c < 4; ++c)
                    wf1[c] = *(const bf16x8*)(WbT + wch[c] + (kc + 1) * 32 + klane);
            }
            bf16x8 af[4];
            #pragma unroll
            for (int r = 0; r < 4; ++r)
                af[r] = *(const bf16x8*)&As[16 * r + ln15][kc * 32 + klane];
            #pragma unroll
            for (int r = 0; r < 4; ++r)
                #pragma unroll
                for (int c = 0; c < 4; ++c)
                    acc[r][c] = __builtin_amdgcn_mfma_f32_16x16x32_bf16(wf0[c], af[r], acc[r][c], 0, 0, 0);
            #pragma unroll
            for (int c = 0; c < 4; ++c) wf0[c] = wf1[c];
        }
    }

    // x4 = ELU(acc + b2) -> PQ park (PQ reads finished before hidden barrier)
    #pragma unroll
    for (int c = 0; c < 4; ++c) {
        float4 bv = *(const float4*)&b2[w * 64 + 16 * c + 4 * q];
        #pragma unroll
        for (int r = 0; r < 4; ++r) {
            ushort4 u;
            u.x = f2bf(elu_f(acc[r][c][0] + bv.x));
            u.y = f2bf(elu_f(acc[r][c][1] + bv.y));
            u.z = f2bf(elu_f(acc[r][c][2] + bv.z));
            u.w = f2bf(elu_f(acc[r][c][3] + bv.w));
            *(ushort4*)&PQ[16 * r + ln15][w * 64 + 16 * c + 4 * q] = u;
        }
    }
    __syncthreads();

    // coalesced global write (in-place over X2 rows of this block)
    #pragma unroll
    for (int m = 0; m < 8; ++m) {
        int ch = tid + m * 256;
        int row = ch >> 5;
        int o = (ch & 31) * 8;
        *(uint4*)&Y[((size_t)(Rbase + row)) * 256 + o] = *(const uint4*)&PQ[row][o];
    }

    // BN-stats epilogue (R4-style LDS loop)
    {
        int c = tid;
        float s = 0.f, q2 = 0.f;
        for (int r = 0; r < 64; ++r) {
            float v = bf2f(PQ[r][c]);
            s += v;
            q2 = fmaf(v, v, q2);
        }
        atomicAdd(&aux[c], s);
        atomicAdd(&aux[256 + c], q2);
    }
}

// ---- fold BN + fc into Wfold[256][2], bfold[2] ----------------------------
__global__ __launch_bounds__(256)
void fold_kernel(const float* __restrict__ stats,
                 const float* __restrict__ gamma, const float* __restrict__ beta,
                 const float* __restrict__ fcW, const float* __restrict__ fcb,
                 float* __restrict__ fold)
{
    __shared__ float red0[256], red1[256];
    int c = threadIdx.x;
    float mean  = stats[c] * (1.f / M_BIG);
    float var   = stats[256 + c] * (1.f / M_BIG) - mean * mean;
    float inv   = rsqrtf(var + 1e-5f);
    float scale = inv * gamma[c];
    float sh    = beta[c] - mean * scale;
    float w0 = fcW[c * 2 + 0], w1 = fcW[c * 2 + 1];
    fold[c * 2 + 0] = scale * w0;
    fold[c * 2 + 1] = scale * w1;
    red0[c] = sh * w0;
    red1[c] = sh * w1;
    __syncthreads();
    for (int off = 128; off > 0; off >>= 1) {
        if (c < off) { red0[c] += red0[c + off]; red1[c] += red1[c + off]; }
        __syncthreads();
    }
    if (c == 0) {
        fold[512] = red0[0] + fcb[0];
        fold[513] = red1[0] + fcb[1];
    }
}

// ---- final: out[R][2] = x4_row . Wfold + bfold  (wave per row) ------------
__global__ __launch_bounds__(256)
void final_kernel(const ushort_t* __restrict__ x4, const float* __restrict__ fold,
                  float* __restrict__ out)
{
    int tid  = threadIdx.x;
    int lane = tid & 63;
    int wave = tid >> 6;
    int R = blockIdx.x * 4 + wave;
    int c0 = lane * 4;
    union { uint2 qv; ushort_t s[4]; } u;
    u.qv = *(const uint2*)(x4 + (size_t)R * 256 + c0);
    float a0 = 0.f, a1 = 0.f;
    #pragma unroll
    for (int j = 0; j < 4; ++j) {
        float v = bf2f(u.s[j]);
        a0 = fmaf(v, fold[(c0 + j) * 2 + 0], a0);
        a1 = fmaf(v, fold[(c0 + j) * 2 + 1], a1);
    }
    #pragma unroll
    for (int off = 32; off > 0; off >>= 1) {
        a0 += __shfl_down(a0, off);
        a1 += __shfl_down(a1, off);
    }
    if (lane == 0) {
        out[(size_t)R * 2 + 0] = a0 + fold[512];
        out[(size_t)R * 2 + 1] = a1 + fold[513];
    }
}

extern "C" void kernel_launch(void* const* d_in, const int* in_sizes, int n_in,
                              void* d_out, int out_size, void* d_ws, size_t ws_size,
                              hipStream_t stream)
{
    (void)in_sizes; (void)n_in; (void)out_size; (void)ws_size;

    const float* inputs = (const float*)d_in[0];
    const float* m1W1 = (const float*)d_in[3];
    const float* m1b1 = (const float*)d_in[4];
    const float* m1W2 = (const float*)d_in[5];
    const float* m1b2 = (const float*)d_in[6];
    const float* m2W1 = (const float*)d_in[7];
    const float* m2b1 = (const float*)d_in[8];
    const float* m2W2 = (const float*)d_in[9];
    const float* m2b2 = (const float*)d_in[10];
    const float* m3W1 = (const float*)d_in[11];
    const float* m3b1 = (const float*)d_in[12];
    const float* m3W2 = (const float*)d_in[13];
    const float* m3b2 = (const float*)d_in[14];
    const float* m4W1 = (const float*)d_in[15];
    const float* m4b1 = (const float*)d_in[16];
    const float* m4W2 = (const float*)d_in[17];
    const float* m4b2 = (const float*)d_in[18];
    const float* gamma = (const float*)d_in[19];
    const float* beta  = (const float*)d_in[20];
    const float* fcW   = (const float*)d_in[21];
    const float* fcb   = (const float*)d_in[22];
    float* out = (float*)d_out;

    // ---- workspace layout (~173 MB) ----
    char* ws = (char*)d_ws;
    const size_t BIGB  = (size_t)M_BIG * 256 * 2;     // 162,201,600
    const size_t SMALL = (size_t)M_SMALL * 256 * 4;   // 3,276,800 (fp32 small)
    const size_t HB    = (size_t)M_SMALL * 256 * 2;   // 1,638,400 (bf16 small)
    ushort_t* bigX     = (ushort_t*)ws;                       // x2 then x4
    float*    hsm      = (float*)(ws + BIGB);                 // h1 then h3 (fp32)
    float*    incoming = (float*)(ws + BIGB + SMALL);
    ushort_t* Pbuf     = (ushort_t*)(ws + BIGB + 2 * SMALL);
    ushort_t* Qbuf     = (ushort_t*)(ws + BIGB + 2 * SMALL + HB);
    float*    stats    = (float*)(ws + BIGB + 2 * SMALL + 2 * HB);
    float*    fold     = stats + 512;
    ushort_t* w2t      = (ushort_t*)(ws + BIGB + 2 * SMALL + 2 * HB + 8192);
    ushort_t* w4at     = w2t + 256 * 256;     // W4a3 (rows 512..767 of m4W1)
    ushort_t* w4bt     = w4at + 256 * 256;

    hipMemsetAsync(stats, 0, 2048, stream);
    hipMemsetAsync(incoming, 0, SMALL, stream);

    dim3 blk(256);
    wcvt3_kernel<<<48, blk, 0, stream>>>(m2W2, m4W1 + 512 * 256, m4W2, w2t, w4at, w4bt);
    // MLP1 -> h1 (fp32)
    fused_small<<<M_SMALL / 64, blk, 0, stream>>>(inputs, 200, 1.f, m1W1, m1b1, m1W2, m1b2, hsm);
    // P2 = h1@W1a + b1, Q2 = h1@W1b
    pq_gemm<<<100, blk, 0, stream>>>(hsm, m2W1, m2W1 + 256 * 256, m2b1, Pbuf, Qbuf);
    // edge MLP2 -> x2 + e2n sums
    edge_mlp2<<<M_BIG / 64, blk, 0, stream>>>(Pbuf, Qbuf, w2t, m2b2, bigX, incoming);
    // MLP3 (incoming/9900) -> h3 (fp32)
    fused_small<<<M_SMALL / 64, blk, 0, stream>>>(incoming, 256, 1.f / 9900.f, m3W1, m3b1, m3W2, m3b2, hsm);
    // P4 = h3@W4a1 + b1, Q4 = h3@W4a2
    pq_gemm<<<100, blk, 0, stream>>>(hsm, m4W1, m4W1 + 256 * 256, m4b1, Pbuf, Qbuf);
    // edge MLP4 -> x4 (in-place) + BN stats
    edge_mlp4<<<M_BIG / 64, blk, 0, stream>>>(Pbuf, Qbuf, bigX, w4at, w4bt, m4b2, bigX, stats);
    // fold + final
    fold_kernel<<<1, blk, 0, stream>>>(stats, gamma, beta, fcW, fcb, fold);
    final_kernel<<<M_BIG / 4, blk, 0, stream>>>(bigX, fold, out);
}

// Round 7
// 860.187 us; speedup vs baseline: 1.6036x; 1.0338x over previous
//
#include <hip/hip_runtime.h>
#include <math.h>

// ---------------------------------------------------------------------------
// MLPEncoder (NRI encoder) on MI355X — round 7: VALU cut + occupancy 2x.
//   concat(h[send],h[recv])@W1  ==  (h@W1a)[send] + (h@W1b)[recv]
//   P2=h1@W1a+b1, Q2=h1@W1b; hidden=ELU(P2[j]+Q2[i]); x2=ELU(hidden@W2+b2)
//   pre=P4[j]+Q4[i]+x2@W4a3;  x4=ELU(ELU(pre)@W4b+b2)   (in-place, BN stats)
// R7 changes vs R6: edge_mlp4's PQ tile removed (per-lane ushort4 loads at
// accumulator positions from L2), __expf everywhere, launch_bounds(256,4)
// on edge kernels (LDS 33.8 KB -> 4 blocks/CU), 512-thread final.
// ---------------------------------------------------------------------------

typedef unsigned short ushort_t;
typedef __bf16 bf16x8 __attribute__((ext_vector_type(8)));
typedef float  f32x4  __attribute__((ext_vector_type(4)));

#define E_EDGES 9900
#define NNODE   100
#define HID     256
#define M_BIG   316800
#define M_SMALL 3200

__device__ __forceinline__ float bf2f(ushort_t u) {
    union { unsigned int i; float f; } v; v.i = ((unsigned int)u) << 16; return v.f;
}
__device__ __forceinline__ ushort_t f2bf(float f) {
    union { float f; unsigned int i; } v; v.f = f;
    return (ushort_t)((v.i + 0x7fffu + ((v.i >> 16) & 1u)) >> 16);   // RNE
}
__device__ __forceinline__ float elu_f(float x) {
    return x > 0.f ? x : (__expf(x) - 1.f);
}

// ---- convert+transpose 3 [256,256] fp32 matrices -> bf16 WT[chan][256] ----
__global__ __launch_bounds__(256)
void wcvt3_kernel(const float* __restrict__ W0, const float* __restrict__ W1,
                  const float* __restrict__ W2,
                  ushort_t* __restrict__ T0, ushort_t* __restrict__ T1,
                  ushort_t* __restrict__ T2)
{
    int bid = blockIdx.x;
    const float* W; ushort_t* WT; int tile;
    if (bid < 16)      { W = W0; WT = T0; tile = bid; }
    else if (bid < 32) { W = W1; WT = T1; tile = bid - 16; }
    else               { W = W2; WT = T2; tile = bid - 32; }
    int k0 = (tile >> 2) * 64, c0 = (tile & 3) * 64;
    __shared__ float S[64][65];
    int t = threadIdx.x;
    #pragma unroll
    for (int i = 0; i < 16; ++i) {
        int idx = t + i * 256;
        S[idx >> 6][idx & 63] = W[(size_t)(k0 + (idx >> 6)) * 256 + c0 + (idx & 63)];
    }
    __syncthreads();
    int col = t & 63;
    int kb  = (t >> 6) * 16;
    ushort_t* dst = WT + (size_t)(c0 + col) * 256 + k0 + kb;
    #pragma unroll
    for (int jj = 0; jj < 4; ++jj) {
        ushort4 u;
        u.x = f2bf(S[kb + 4 * jj + 0][col]);
        u.y = f2bf(S[kb + 4 * jj + 1][col]);
        u.z = f2bf(S[kb + 4 * jj + 2][col]);
        u.w = f2bf(S[kb + 4 * jj + 3][col]);
        *(ushort4*)(dst + 4 * jj) = u;
    }
}

// ---- fused small 2-layer fp32 MLP: X[3200,K0] -> ELU MLP -> fp32 [3200,256]
#define FMA_ROW(ri, xs) \
    acc[ri][0] = fmaf(xs, w.x, acc[ri][0]); \
    acc[ri][1] = fmaf(xs, w.y, acc[ri][1]); \
    acc[ri][2] = fmaf(xs, w.z, acc[ri][2]); \
    acc[ri][3] = fmaf(xs, w.w, acc[ri][3]);

__global__ __launch_bounds__(256, 2)
void fused_small(const float* __restrict__ X, int K0, float xscale,
                 const float* __restrict__ W1, const float* __restrict__ b1,
                 const float* __restrict__ W2, const float* __restrict__ b2,
                 float* __restrict__ Yf)
{
    __shared__ float Xs[32][68];
    __shared__ float Ws[32][256];
    __shared__ float Hs[64][257];
    const int tid = threadIdx.x;
    const int Rbase = blockIdx.x * 64;
    const int c0 = (tid & 63) * 4;
    const int r0 = (tid >> 6) * 16;
    const int r_st = tid & 63;
    const int kb = (tid >> 6) * 8;

    float acc[16][4];
    #pragma unroll
    for (int i = 0; i < 16; ++i)
        #pragma unroll
        for (int j = 0; j < 4; ++j) acc[i][j] = 0.f;

    const int nch = (K0 + 31) >> 5;
    for (int kc = 0; kc < nch; ++kc) {
        if (kc) __syncthreads();
        {
            int kg = kc * 32 + kb;
            const float* p = X + (size_t)(Rbase + r_st) * K0 + kg;
            float v[8];
            if (kg + 8 <= K0) {
                float4 a = *(const float4*)p;
                float4 b = *(const float4*)(p + 4);
                v[0]=a.x; v[1]=a.y; v[2]=a.z; v[3]=a.w;
                v[4]=b.x; v[5]=b.y; v[6]=b.z; v[7]=b.w;
            } else {
                #pragma unroll
                for (int j = 0; j < 8; ++j) v[j] = (kg + j < K0) ? p[j] : 0.f;
            }
            #pragma unroll
            for (int j = 0; j < 8; ++j) Xs[kb + j][r_st] = v[j];
        }
        #pragma unroll
        for (int m = 0; m < 8; ++m) {
            int f  = tid + m * 256;
            int kk = f >> 6;
            int cc = (f & 63) * 4;
            int kg = kc * 32 + kk;
            float4 w = (kg < K0) ? *(const float4*)&W1[(size_t)kg * 256 + cc]
                                 : make_float4(0.f, 0.f, 0.f, 0.f);
            *(float4*)&Ws[kk][cc] = w;
        }
        __syncthreads();
        #pragma unroll 8
        for (int kk = 0; kk < 32; ++kk) {
            float4 w = *(const float4*)&Ws[kk][c0];
            #pragma unroll
            for (int i = 0; i < 4; ++i) {
                float4 x = *(const float4*)&Xs[kk][r0 + 4 * i];
                FMA_ROW(4 * i + 0, x.x)
                FMA_ROW(4 * i + 1, x.y)
                FMA_ROW(4 * i + 2, x.z)
                FMA_ROW(4 * i + 3, x.w)
            }
        }
    }
    {
        float4 bv = *(const float4*)&b1[c0];
        #pragma unroll
        for (int i = 0; i < 16; ++i) {
            Hs[r0 + i][c0 + 0] = elu_f(acc[i][0] * xscale + bv.x);
            Hs[r0 + i][c0 + 1] = elu_f(acc[i][1] * xscale + bv.y);
            Hs[r0 + i][c0 + 2] = elu_f(acc[i][2] * xscale + bv.z);
            Hs[r0 + i][c0 + 3] = elu_f(acc[i][3] * xscale + bv.w);
        }
    }
    #pragma unroll
    for (int i = 0; i < 16; ++i)
        #pragma unroll
        for (int j = 0; j < 4; ++j) acc[i][j] = 0.f;
    for (int kc = 0; kc < 8; ++kc) {
        __syncthreads();
        {
            #pragma unroll
            for (int j = 0; j < 8; ++j) Xs[kb + j][r_st] = Hs[r_st][kc * 32 + kb + j];
        }
        #pragma unroll
        for (int m = 0; m < 8; ++m) {
            int f  = tid + m * 256;
            int kk = f >> 6;
            int cc = (f & 63) * 4;
            *(float4*)&Ws[kk][cc] = *(const float4*)&W2[(size_t)(kc * 32 + kk) * 256 + cc];
        }
        __syncthreads();
        #pragma unroll 8
        for (int kk = 0; kk < 32; ++kk) {
            float4 w = *(const float4*)&Ws[kk][c0];
            #pragma unroll
            for (int i = 0; i < 4; ++i) {
                float4 x = *(const float4*)&Xs[kk][r0 + 4 * i];
                FMA_ROW(4 * i + 0, x.x)
                FMA_ROW(4 * i + 1, x.y)
                FMA_ROW(4 * i + 2, x.z)
                FMA_ROW(4 * i + 3, x.w)
            }
        }
    }
    {
        float4 bv = *(const float4*)&b2[c0];
        #pragma unroll
        for (int i = 0; i < 16; ++i) {
            int R = Rbase + r0 + i;
            *(float4*)&Yf[(size_t)R * 256 + c0] = make_float4(
                elu_f(acc[i][0] + bv.x), elu_f(acc[i][1] + bv.y),
                elu_f(acc[i][2] + bv.z), elu_f(acc[i][3] + bv.w));
        }
    }
}

// ---- P/Q partial GEMMs: P = X@Wa + biasA (no act), Q = X@Wb (bf16 out) ----
__global__ __launch_bounds__(256, 2)
void pq_gemm(const float* __restrict__ X,
             const float* __restrict__ Wa, const float* __restrict__ Wb_,
             const float* __restrict__ biasA,
             ushort_t* __restrict__ Yp, ushort_t* __restrict__ Yq)
{
    const int bid = blockIdx.x;
    const float* W; const float* bias; ushort_t* Y; int Rbase;
    if (bid < 50) { W = Wa;  bias = biasA;  Y = Yp; Rbase = bid * 64; }
    else          { W = Wb_; bias = nullptr; Y = Yq; Rbase = (bid - 50) * 64; }

    __shared__ float Xs[32][68];
    __shared__ float Ws[32][256];
    const int tid = threadIdx.x;
    const int c0 = (tid & 63) * 4;
    const int r0 = (tid >> 6) * 16;
    const int r_st = tid & 63;
    const int kb = (tid >> 6) * 8;

    float acc[16][4];
    #pragma unroll
    for (int i = 0; i < 16; ++i)
        #pragma unroll
        for (int j = 0; j < 4; ++j) acc[i][j] = 0.f;

    for (int kc = 0; kc < 8; ++kc) {
        if (kc) __syncthreads();
        {
            const float* p = X + (size_t)(Rbase + r_st) * 256 + kc * 32 + kb;
            float4 a = *(const float4*)p;
            float4 b = *(const float4*)(p + 4);
            Xs[kb + 0][r_st] = a.x; Xs[kb + 1][r_st] = a.y;
            Xs[kb + 2][r_st] = a.z; Xs[kb + 3][r_st] = a.w;
            Xs[kb + 4][r_st] = b.x; Xs[kb + 5][r_st] = b.y;
            Xs[kb + 6][r_st] = b.z; Xs[kb + 7][r_st] = b.w;
        }
        #pragma unroll
        for (int m = 0; m < 8; ++m) {
            int f  = tid + m * 256;
            int kk = f >> 6;
            int cc = (f & 63) * 4;
            *(float4*)&Ws[kk][cc] = *(const float4*)&W[(size_t)(kc * 32 + kk) * 256 + cc];
        }
        __syncthreads();
        #pragma unroll 8
        for (int kk = 0; kk < 32; ++kk) {
            float4 w = *(const float4*)&Ws[kk][c0];
            #pragma unroll
            for (int i = 0; i < 4; ++i) {
                float4 x = *(const float4*)&Xs[kk][r0 + 4 * i];
                FMA_ROW(4 * i + 0, x.x)
                FMA_ROW(4 * i + 1, x.y)
                FMA_ROW(4 * i + 2, x.z)
                FMA_ROW(4 * i + 3, x.w)
            }
        }
    }
    float4 bv = bias ? *(const float4*)&bias[c0] : make_float4(0.f, 0.f, 0.f, 0.f);
    #pragma unroll
    for (int i = 0; i < 16; ++i) {
        int R = Rbase + r0 + i;
        ushort4 u;
        u.x = f2bf(acc[i][0] + bv.x);
        u.y = f2bf(acc[i][1] + bv.y);
        u.z = f2bf(acc[i][2] + bv.z);
        u.w = f2bf(acc[i][3] + bv.w);
        *(ushort4*)&Y[(size_t)R * 256 + c0] = u;
    }
}

// ---- edge kernel A (MLP2): hidden=ELU(P[j]+Q[i]); x2=ELU(hidden@W2+b2) ----
__global__ __launch_bounds__(256, 4)
void edge_mlp2(const ushort_t* __restrict__ Pb, const ushort_t* __restrict__ Qb,
               const ushort_t* __restrict__ W2T,   // [chan][256] bf16
               const float* __restrict__ b2,
               ushort_t* __restrict__ Y, float* __restrict__ aux)
{
    __shared__ ushort_t As[64][264];    // hidden, then x2 park
    const int tid = threadIdx.x;
    const int w = tid >> 6;
    const int l = tid & 63;
    const int ln15 = l & 15;
    const int q = l >> 4;
    const int klane = 8 * q;
    const int Rbase = blockIdx.x * 64;

    // phase 1: hidden tile (coalesced row gathers of P/Q, elementwise ELU)
    {
        int row = tid >> 2;
        int R = Rbase + row;
        int b = R / E_EDGES;
        int e = R - b * E_EDGES;
        int i = e / 99;
        int k = e - 99 * i;
        int j = k + (k >= i ? 1 : 0);
        const ushort_t* prow = Pb + (size_t)(b * NNODE + j) * HID;
        const ushort_t* qrow = Qb + (size_t)(b * NNODE + i) * HID;
        int off = (tid & 3) * 8;
        #pragma unroll
        for (int u = 0; u < 8; ++u) {
            int o = off + u * 32;
            union { uint4 v; ushort_t s[8]; } pu, qu, hu;
            pu.v = *(const uint4*)(prow + o);
            qu.v = *(const uint4*)(qrow + o);
            #pragma unroll
            for (int x = 0; x < 8; ++x)
                hu.s[x] = f2bf(elu_f(bf2f(pu.s[x]) + bf2f(qu.s[x])));
            *(uint4*)&As[row][o] = hu.v;
        }
    }
    __syncthreads();

    // GEMM: acc = hidden @ W2 (swapped-operand MFMA, W-frags from L2)
    f32x4 acc[4][4];
    #pragma unroll
    for (int r = 0; r < 4; ++r)
        #pragma unroll
        for (int c = 0; c < 4; ++c)
            acc[r][c][0] = acc[r][c][1] = acc[r][c][2] = acc[r][c][3] = 0.f;
    int wch[4];
    #pragma unroll
    for (int c = 0; c < 4; ++c) wch[c] = (w * 64 + 16 * c + ln15) * 256;
    {
        bf16x8 wf0[4];
        #pragma unroll
        for (int c = 0; c < 4; ++c)
            wf0[c] = *(const bf16x8*)(W2T + wch[c] + klane);
        #pragma unroll
        for (int kc = 0; kc < 8; ++kc) {
            bf16x8 wf1[4];
            if (kc < 7) {
                #pragma unroll
                for (int c = 0; c < 4; ++c)
                    wf1[c] = *(const bf16x8*)(W2T + wch[c] + (kc + 1) * 32 + klane);
            }
            bf16x8 af[4];
            #pragma unroll
            for (int r = 0; r < 4; ++r)
                af[r] = *(const bf16x8*)&As[16 * r + ln15][kc * 32 + klane];
            #pragma unroll
            for (int r = 0; r < 4; ++r)
                #pragma unroll
                for (int c = 0; c < 4; ++c)
                    acc[r][c] = __builtin_amdgcn_mfma_f32_16x16x32_bf16(wf0[c], af[r], acc[r][c], 0, 0, 0);
            #pragma unroll
            for (int c = 0; c < 4; ++c) wf0[c] = wf1[c];
        }
    }
    __syncthreads();    // hidden reads done

    // park x2 = ELU(acc + b2)  (lane: edge=16r+ln15, chans w*64+16c+4q+g)
    #pragma unroll
    for (int c = 0; c < 4; ++c) {
        float4 bv = *(const float4*)&b2[w * 64 + 16 * c + 4 * q];
        #pragma unroll
        for (int r = 0; r < 4; ++r) {
            ushort4 u;
            u.x = f2bf(elu_f(acc[r][c][0] + bv.x));
            u.y = f2bf(elu_f(acc[r][c][1] + bv.y));
            u.z = f2bf(elu_f(acc[r][c][2] + bv.z));
            u.w = f2bf(elu_f(acc[r][c][3] + bv.w));
            *(ushort4*)&As[16 * r + ln15][w * 64 + 16 * c + 4 * q] = u;
        }
    }
    __syncthreads();

    // coalesced global write
    #pragma unroll
    for (int m = 0; m < 8; ++m) {
        int ch = tid + m * 256;
        int row = ch >> 5;
        int o = (ch & 31) * 8;
        *(uint4*)&Y[((size_t)(Rbase + row)) * 256 + o] = *(const uint4*)&As[row][o];
    }

    // e2n epilogue (LDS loop; receiver segments are contiguous)
    {
        int c = tid;
        int bn = Rbase / 99;
        int left = 99 - (Rbase - bn * 99);
        float s = 0.f;
        for (int r = 0; r < 64; ++r) {
            s += bf2f(As[r][c]);
            if (--left == 0) { atomicAdd(&aux[(size_t)bn * 256 + c], s); s = 0.f; ++bn; left = 99; }
        }
        atomicAdd(&aux[(size_t)bn * 256 + c], s);
    }
}

// ---- edge kernel B (MLP4): pre=P[j]+Q[i]+x2@W4a3; x4=ELU(ELU(pre)@W4b+b2) -
// Single LDS tile; P/Q read per-lane (ushort4, L2) at accumulator positions.
__global__ __launch_bounds__(256, 4)
void edge_mlp4(const ushort_t* __restrict__ Pb, const ushort_t* __restrict__ Qb,
               const ushort_t* __restrict__ X2,
               const ushort_t* __restrict__ WaT,   // [chan][256] bf16
               const ushort_t* __restrict__ WbT,   // [chan][256] bf16
               const float* __restrict__ b2,
               ushort_t* __restrict__ Y, float* __restrict__ aux)
{
    __shared__ ushort_t As[64][264];    // x2 tile -> hidden -> x4 park
    const int tid = threadIdx.x;
    const int w = tid >> 6;
    const int l = tid & 63;
    const int ln15 = l & 15;
    const int q = l >> 4;
    const int klane = 8 * q;
    const int Rbase = blockIdx.x * 64;

    // phase 0: stage x2 tile (coalesced)
    {
        int row = tid >> 2;
        const ushort_t* xrow = X2 + (size_t)(Rbase + row) * 256;
        int off = (tid & 3) * 8;
        #pragma unroll
        for (int u = 0; u < 8; ++u) {
            int o = off + u * 32;
            *(uint4*)&As[row][o] = *(const uint4*)(xrow + o);
        }
    }

    // per-lane P/Q row offsets for its 4 row-tiles
    int oP[4], oQ[4];
    #pragma unroll
    for (int r = 0; r < 4; ++r) {
        int R = Rbase + 16 * r + ln15;
        int b = R / E_EDGES;
        int e = R - b * E_EDGES;
        int i = e / 99;
        int k = e - 99 * i;
        int j = k + (k >= i ? 1 : 0);
        oP[r] = (b * NNODE + j) * HID;
        oQ[r] = (b * NNODE + i) * HID;
    }
    __syncthreads();

    f32x4 acc[4][4];
    int wch[4];
    #pragma unroll
    for (int c = 0; c < 4; ++c) wch[c] = (w * 64 + 16 * c + ln15) * 256;

    // L1 GEMM: acc = x2tile @ W4a3
    #pragma unroll
    for (int r = 0; r < 4; ++r)
        #pragma unroll
        for (int c = 0; c < 4; ++c)
            acc[r][c][0] = acc[r][c][1] = acc[r][c][2] = acc[r][c][3] = 0.f;
    {
        bf16x8 wf0[4];
        #pragma unroll
        for (int c = 0; c < 4; ++c)
            wf0[c] = *(const bf16x8*)(WaT + wch[c] + klane);
        #pragma unroll
        for (int kc = 0; kc < 8; ++kc) {
            bf16x8 wf1[4];
            if (kc < 7) {
                #pragma unroll
                for (int c = 0; c < 4; ++c)
                    wf1[c] = *(const bf16x8*)(WaT + wch[c] + (kc + 1) * 32 + klane);
            }
            bf16x8 af[4];
            #pragma unroll
            for (int r = 0; r < 4; ++r)
                af[r] = *(const bf16x8*)&As[16 * r + ln15][kc * 32 + klane];
            #pragma unroll
            for (int r = 0; r < 4; ++r)
                #pragma unroll
                for (int c = 0; c < 4; ++c)
                    acc[r][c] = __builtin_amdgcn_mfma_f32_16x16x32_bf16(wf0[c], af[r], acc[r][c], 0, 0, 0);
            #pragma unroll
            for (int c = 0; c < 4; ++c) wf0[c] = wf1[c];
        }
    }
    __syncthreads();    // x2 tile reads done

    // hidden = ELU(acc + P[j] + Q[i]) -> As   (P/Q: per-lane ushort4 from L2)
    #pragma unroll
    for (int c = 0; c < 4; ++c) {
        int ch = w * 64 + 16 * c + 4 * q;
        #pragma unroll
        for (int r = 0; r < 4; ++r) {
            union { ushort4 v; ushort_t s[4]; } pu, qu;
            pu.v = *(const ushort4*)(Pb + oP[r] + ch);
            qu.v = *(const ushort4*)(Qb + oQ[r] + ch);
            ushort4 u;
            u.x = f2bf(elu_f(acc[r][c][0] + bf2f(pu.s[0]) + bf2f(qu.s[0])));
            u.y = f2bf(elu_f(acc[r][c][1] + bf2f(pu.s[1]) + bf2f(qu.s[1])));
            u.z = f2bf(elu_f(acc[r][c][2] + bf2f(pu.s[2]) + bf2f(qu.s[2])));
            u.w = f2bf(elu_f(acc[r][c][3] + bf2f(pu.s[3]) + bf2f(qu.s[3])));
            *(ushort4*)&As[16 * r + ln15][ch] = u;
        }
    }
    __syncthreads();

    // L2 GEMM: acc = hidden @ W4b
    #pragma unroll
    for (int r = 0; r < 4; ++r)
        #pragma unroll
        for (int c = 0; c < 4; ++c)
            acc[r][c][0] = acc[r][c][1] = acc[r][c][2] = acc[r][c][3] = 0.f;
    {
        bf16x8 wf0[4];
        #pragma unroll
        for (int c = 0; c < 4; ++c)
            wf0[c] = *(const bf16x8*)(WbT + wch[c] + klane);
        #pragma unroll
        for (int kc = 0; kc < 8; ++kc) {
            bf16x8 wf1[4];
            if (kc < 7) {
                #pragma unroll
                for (int c = 0; c < 4; ++c)
                    wf1[c] = *(const bf16x8*)(WbT + wch[c] + (kc + 1) * 32 + klane);
            }
            bf16x8 af[4];
            #pragma unroll
            for (int r = 0; r < 4; ++r)
                af[r] = *(const bf16x8*)&As[16 * r + ln15][kc * 32 + klane];
            #pragma unroll
            for (int r = 0; r < 4; ++r)
                #pragma unroll
                for (int c = 0; c < 4; ++c)
                    acc[r][c] = __builtin_amdgcn_mfma_f32_16x16x32_bf16(wf0[c], af[r], acc[r][c], 0, 0, 0);
            #pragma unroll
            for (int c = 0; c < 4; ++c) wf0[c] = wf1[c];
        }
    }
    __syncthreads();    // hidden reads done before park overwrite

    // x4 = ELU(acc + b2) -> As park
    #pragma unroll
    for (int c = 0; c < 4; ++c) {
        float4 bv = *(const float4*)&b2[w * 64 + 16 * c + 4 * q];
        #pragma unroll
        for (int r = 0; r < 4; ++r) {
            ushort4 u;
            u.x = f2bf(elu_f(acc[r][c][0] + bv.x));
            u.y = f2bf(elu_f(acc[r][c][1] + bv.y));
            u.z = f2bf(elu_f(acc[r][c][2] + bv.z));
            u.w = f2bf(elu_f(acc[r][c][3] + bv.w));
            *(ushort4*)&As[16 * r + ln15][w * 64 + 16 * c + 4 * q] = u;
        }
    }
    __syncthreads();

    // coalesced global write (in-place over X2 rows of this block)
    #pragma unroll
    for (int m = 0; m < 8; ++m) {
        int ch = tid + m * 256;
        int row = ch >> 5;
        int o = (ch & 31) * 8;
        *(uint4*)&Y[((size_t)(Rbase + row)) * 256 + o] = *(const uint4*)&As[row][o];
    }

    // BN-stats epilogue (LDS loop)
    {
        int c = tid;
        float s = 0.f, q2 = 0.f;
        for (int r = 0; r < 64; ++r) {
            float v = bf2f(As[r][c]);
            s += v;
            q2 = fmaf(v, v, q2);
        }
        atomicAdd(&aux[c], s);
        atomicAdd(&aux[256 + c], q2);
    }
}

// ---- fold BN + fc into Wfold[256][2], bfold[2] ----------------------------
__global__ __launch_bounds__(256)
void fold_kernel(const float* __restrict__ stats,
                 const float* __restrict__ gamma, const float* __restrict__ beta,
                 const float* __restrict__ fcW, const float* __restrict__ fcb,
                 float* __restrict__ fold)
{
    __shared__ float red0[256], red1[256];
    int c = threadIdx.x;
    float mean  = stats[c] * (1.f / M_BIG);
    float var   = stats[256 + c] * (1.f / M_BIG) - mean * mean;
    float inv   = rsqrtf(var + 1e-5f);
    float scale = inv * gamma[c];
    float sh    = beta[c] - mean * scale;
    float w0 = fcW[c * 2 + 0], w1 = fcW[c * 2 + 1];
    fold[c * 2 + 0] = scale * w0;
    fold[c * 2 + 1] = scale * w1;
    red0[c] = sh * w0;
    red1[c] = sh * w1;
    __syncthreads();
    for (int off = 128; off > 0; off >>= 1) {
        if (c < off) { red0[c] += red0[c + off]; red1[c] += red1[c + off]; }
        __syncthreads();
    }
    if (c == 0) {
        fold[512] = red0[0] + fcb[0];
        fold[513] = red1[0] + fcb[1];
    }
}

// ---- final: out[R][2] = x4_row . Wfold + bfold  (wave per row, 8 rows/blk) -
__global__ __launch_bounds__(512)
void final_kernel(const ushort_t* __restrict__ x4, const float* __restrict__ fold,
                  float* __restrict__ out)
{
    int tid  = threadIdx.x;
    int lane = tid & 63;
    int wave = tid >> 6;
    int R = blockIdx.x * 8 + wave;
    int c0 = lane * 4;
    union { uint2 qv; ushort_t s[4]; } u;
    u.qv = *(const uint2*)(x4 + (size_t)R * 256 + c0);
    float a0 = 0.f, a1 = 0.f;
    #pragma unroll
    for (int j = 0; j < 4; ++j) {
        float v = bf2f(u.s[j]);
        a0 = fmaf(v, fold[(c0 + j) * 2 + 0], a0);
        a1 = fmaf(v, fold[(c0 + j) * 2 + 1], a1);
    }
    #pragma unroll
    for (int off = 32; off > 0; off >>= 1) {
        a0 += __shfl_down(a0, off);
        a1 += __shfl_down(a1, off);
    }
    if (lane == 0) {
        out[(size_t)R * 2 + 0] = a0 + fold[512];
        out[(size_t)R * 2 + 1] = a1 + fold[513];
    }
}

extern "C" void kernel_launch(void* const* d_in, const int* in_sizes, int n_in,
                              void* d_out, int out_size, void* d_ws, size_t ws_size,
                              hipStream_t stream)
{
    (void)in_sizes; (void)n_in; (void)out_size; (void)ws_size;

    const float* inputs = (const float*)d_in[0];
    const float* m1W1 = (const float*)d_in[3];
    const float* m1b1 = (const float*)d_in[4];
    const float* m1W2 = (const float*)d_in[5];
    const float* m1b2 = (const float*)d_in[6];
    const float* m2W1 = (const float*)d_in[7];
    const float* m2b1 = (const float*)d_in[8];
    const float* m2W2 = (const float*)d_in[9];
    const float* m2b2 = (const float*)d_in[10];
    const float* m3W1 = (const float*)d_in[11];
    const float* m3b1 = (const float*)d_in[12];
    const float* m3W2 = (const float*)d_in[13];
    const float* m3b2 = (const float*)d_in[14];
    const float* m4W1 = (const float*)d_in[15];
    const float* m4b1 = (const float*)d_in[16];
    const float* m4W2 = (const float*)d_in[17];
    const float* m4b2 = (const float*)d_in[18];
    const float* gamma = (const float*)d_in[19];
    const float* beta  = (const float*)d_in[20];
    const float* fcW   = (const float*)d_in[21];
    const float* fcb   = (const float*)d_in[22];
    float* out = (float*)d_out;

    // ---- workspace layout (~173 MB) ----
    char* ws = (char*)d_ws;
    const size_t BIGB  = (size_t)M_BIG * 256 * 2;     // 162,201,600
    const size_t SMALL = (size_t)M_SMALL * 256 * 4;   // 3,276,800 (fp32 small)
    const size_t HB    = (size_t)M_SMALL * 256 * 2;   // 1,638,400 (bf16 small)
    ushort_t* bigX     = (ushort_t*)ws;                       // x2 then x4
    float*    hsm      = (float*)(ws + BIGB);                 // h1 then h3 (fp32)
    float*    incoming = (float*)(ws + BIGB + SMALL);
    ushort_t* Pbuf     = (ushort_t*)(ws + BIGB + 2 * SMALL);
    ushort_t* Qbuf     = (ushort_t*)(ws + BIGB + 2 * SMALL + HB);
    float*    stats    = (float*)(ws + BIGB + 2 * SMALL + 2 * HB);
    float*    fold     = stats + 512;
    ushort_t* w2t      = (ushort_t*)(ws + BIGB + 2 * SMALL + 2 * HB + 8192);
    ushort_t* w4at     = w2t + 256 * 256;     // W4a3 (rows 512..767 of m4W1)
    ushort_t* w4bt     = w4at + 256 * 256;

    hipMemsetAsync(stats, 0, 2048, stream);
    hipMemsetAsync(incoming, 0, SMALL, stream);

    dim3 blk(256);
    wcvt3_kernel<<<48, blk, 0, stream>>>(m2W2, m4W1 + 512 * 256, m4W2, w2t, w4at, w4bt);
    // MLP1 -> h1 (fp32)
    fused_small<<<M_SMALL / 64, blk, 0, stream>>>(inputs, 200, 1.f, m1W1, m1b1, m1W2, m1b2, hsm);
    // P2 = h1@W1a + b1, Q2 = h1@W1b
    pq_gemm<<<100, blk, 0, stream>>>(hsm, m2W1, m2W1 + 256 * 256, m2b1, Pbuf, Qbuf);
    // edge MLP2 -> x2 + e2n sums
    edge_mlp2<<<M_BIG / 64, blk, 0, stream>>>(Pbuf, Qbuf, w2t, m2b2, bigX, incoming);
    // MLP3 (incoming/9900) -> h3 (fp32)
    fused_small<<<M_SMALL / 64, blk, 0, stream>>>(incoming, 256, 1.f / 9900.f, m3W1, m3b1, m3W2, m3b2, hsm);
    // P4 = h3@W4a1 + b1, Q4 = h3@W4a2
    pq_gemm<<<100, blk, 0, stream>>>(hsm, m4W1, m4W1 + 256 * 256, m4b1, Pbuf, Qbuf);
    // edge MLP4 -> x4 (in-place) + BN stats
    edge_mlp4<<<M_BIG / 64, blk, 0, stream>>>(Pbuf, Qbuf, bigX, w4at, w4bt, m4b2, bigX, stats);
    // fold + final
    fold_kernel<<<1, blk, 0, stream>>>(stats, gamma, beta, fcW, fcb, fold);
    final_kernel<<<M_BIG / 8, dim3(512), 0, stream>>>(bigX, fold, out);
}